// Round 8
// baseline (372.508 us; speedup 1.0000x reference)
//
#include <hip/hip_runtime.h>
#include <hip/hip_cooperative_groups.h>
#include <stdint.h>
namespace cg = cooperative_groups;

#define CONF 0.96f
#define IOUT 0.45f
#define NA 25200
#define DIM 85
#define NC 80
#define NIMG 8
#define NCAND 2048
#define CAPRAW 4096
#define NDET 300
#define CSTRIDE 32                    // cnt[img*CSTRIDE]: 128 B between counters
#define CH 64                         // mask tile edge
#define NCH (NCAND / CH)              // 32 chunks
#define APB 112                       // anchors per filter tile
#define NT1 (NA / APB)                // 225 filter tiles per image
#define BCAP 256
#define NBLK 256
#define NTHR 256

// One cooperative kernel, 4 phases, 3 grid syncs. 256 blocks x 256 thr =
// 1 block/CU guaranteed co-resident. Phase bodies are the R7 kernels
// verbatim; no thread returns before the last grid.sync().
__global__ __launch_bounds__(NTHR) void mega(
    const float* __restrict__ pred, float* __restrict__ out,
    int* cnt, int* n_arr, float* raw_s, int* raw_f,
    float* score, int* label,
    float* ox1, float* oy1, float* ox2, float* oy2, float* area,
    float* rx1, float* ry1, float* rx2, float* ry2,
    uint64_t* mask64) {
    cg::grid_group grid = cg::this_grid();
    __shared__ alignas(16) unsigned char smem[40192];   // union of all phases
    int tid = threadIdx.x;
    int blk = blockIdx.x;

    // ================= P1: filter (R7 k1, tile loop over 1800) =========
    {
        float* tile = (float*)smem;                     // 38080 B
        float* l_s  = (float*)(smem + 38080);           // 1024 B
        int*   l_f  = (int*)  (smem + 38080 + 1024);    // 1024 B
        int*   l_c  = (int*)  (smem + 38080 + 2048);    // [0]=cnt [1]=base
        for (int t = blk; t < NT1 * NIMG; t += NBLK) {
            int img = t / NT1;
            int a0 = (t - img * NT1) * APB;
            if (tid == 0) l_c[0] = 0;
            __syncthreads();
            const float4* src = (const float4*)(pred + ((size_t)img * NA + a0) * DIM);
            float4* dst = (float4*)tile;
            for (int i = tid; i < (APB * DIM / 4); i += NTHR) dst[i] = src[i];
            __syncthreads();
            for (int it = 0; it < (APB * NC / NTHR); ++it) {
                int wI = tid + it * NTHR;
                int al = wI / NC;
                int c  = wI - al * NC;
                float obj = tile[al * DIM + 4];
                float s = tile[al * DIM + 5 + c] * obj;
                if (s > CONF && obj > CONF) {
                    int p = atomicAdd(&l_c[0], 1);
                    if (p < BCAP) { l_s[p] = s; l_f[p] = (a0 + al) * NC + c; }
                }
            }
            __syncthreads();
            int c = l_c[0]; if (c > BCAP) c = BCAP;
            if (tid == 0) l_c[1] = c ? atomicAdd(&cnt[img * CSTRIDE], c) : 0;
            __syncthreads();
            int base = l_c[1];
            for (int i = tid; i < c; i += NTHR) {
                int pos = base + i;
                if (pos < CAPRAW) {
                    raw_s[img * CAPRAW + pos] = l_s[i];
                    raw_f[img * CAPRAW + pos] = l_f[i];
                }
            }
            __syncthreads();          // protect tile before next stage
        }
    }
    __threadfence();
    grid.sync();

    // ================= P2: rank sort (R7 k2, blocks 0..127) ============
    if (blk < NIMG * (CAPRAW / NTHR)) {                 // 128 units
        uint64_t* keys = (uint64_t*)smem;               // 32 KB
        int img = blk >> 4;
        int unit = blk & 15;
        int m = cnt[img * CSTRIDE]; if (m > CAPRAW) m = CAPRAW;
        if (unit == 0 && tid == 0) n_arr[img] = m < NCAND ? m : NCAND;
        const float* rs = raw_s + img * CAPRAW;
        const int*   rf = raw_f + img * CAPRAW;
        for (int j = tid; j < CAPRAW; j += NTHR) {
            uint64_t k = 0;
            if (j < m)
                k = ((uint64_t)__float_as_uint(rs[j]) << 32) | (uint32_t)(~(uint32_t)rf[j]);
            keys[j] = k;
        }
        __syncthreads();
        if (unit * NTHR < m) {
            int idx = unit * NTHR + tid;
            bool valid = idx < m;
            uint64_t my = keys[idx];                    // 0 for invalid
            int mt = (m + 7) & ~7;                      // pad keys 0: never >
            int rank = 0;
#pragma unroll 8
            for (int j = 0; j < mt; ++j) rank += (keys[j] > my) ? 1 : 0;
            if (valid && rank < NCAND) {
                float s = __uint_as_float((uint32_t)(my >> 32));
                uint32_t myf = ~((uint32_t)my);
                int anchor = (int)(myf / NC);
                int lab = (int)(myf - (uint32_t)anchor * NC);
                const float* p = pred + ((size_t)img * NA + anchor) * DIM;
                float cx = p[0], cy = p[1], wv = p[2], hv = p[3];
                float x1 = cx - 0.5f * wv, y1 = cy - 0.5f * hv;
                float x2 = cx + 0.5f * wv, y2 = cy + 0.5f * hv;
                float off = (float)lab * 4.0f;
                size_t o = (size_t)img * NCAND + rank;
                score[o] = s; label[o] = lab;
                rx1[o] = x1; ry1[o] = y1; rx2[o] = x2; ry2[o] = y2;
                float o1 = x1 + off, o2 = y1 + off, o3 = x2 + off, o4 = y2 + off;
                ox1[o] = o1; oy1[o] = o2; ox2[o] = o3; oy2[o] = o4;
                area[o] = (o3 - o1) * (o4 - o2);        // same op order as ref
            }
        }
    }
    __threadfence();
    grid.sync();

    // ================= P3: mask tiles (R7 k3; ALL 1024 tiles/img) ======
    // Inactive tiles (below diagonal / past n) store literal 0 -> no
    // memset needed; every (row,word) of mask is written exactly once.
    {
        int wv = tid >> 6, lane = tid & 63;
        float* jx1 = (float*)smem + (wv * 5 + 0) * 64;
        float* jy1 = (float*)smem + (wv * 5 + 1) * 64;
        float* jx2 = (float*)smem + (wv * 5 + 2) * 64;
        float* jy2 = (float*)smem + (wv * 5 + 3) * 64;
        float* jar = (float*)smem + (wv * 5 + 4) * 64;
        for (int it = 0; it < 8; ++it) {                // 8192 wave-tiles
            int T = it * (NBLK * 4) + blk * 4 + wv;
            int img = T >> 10;
            int r = T & 1023;
            int ci = r >> 5, cj = r & 31;
            int n = n_arr[img];
            size_t base = (size_t)img * NCAND;
            bool active = (cj >= ci) && (ci * CH < n) && (cj * CH < n);
            if (active) {
                int j = cj * CH + lane;
                float x1 = 0.f, y1 = 0.f, x2 = 0.f, y2 = 0.f, ar = 0.f;
                if (j < n) {
                    x1 = ox1[base + j]; y1 = oy1[base + j];
                    x2 = ox2[base + j]; y2 = oy2[base + j]; ar = area[base + j];
                }
                jx1[lane] = x1; jy1[lane] = y1; jx2[lane] = x2;
                jy2[lane] = y2; jar[lane] = ar;
            }
            __syncthreads();                            // uniform (8 iters all)
            uint64_t w = 0;
            int i = ci * CH + lane;
            if (active) {
                float ax1 = 0.f, ay1 = 0.f, ax2 = 0.f, ay2 = 0.f, aar = 0.f;
                if (i < n) {
                    ax1 = ox1[base + i]; ay1 = oy1[base + i];
                    ax2 = ox2[base + i]; ay2 = oy2[base + i]; aar = area[base + i];
                }
                int jg0 = cj * CH;
#pragma unroll 8
                for (int jj = 0; jj < CH; ++jj) {
                    float ltx = fmaxf(ax1, jx1[jj]), lty = fmaxf(ay1, jy1[jj]);
                    float rbx = fminf(ax2, jx2[jj]), rby = fminf(ay2, jy2[jj]);
                    float ww = fmaxf(rbx - ltx, 0.f), hh = fmaxf(rby - lty, 0.f);
                    float inter = ww * hh;
                    float iou = inter / (aar + jar[jj] - inter + 1e-9f); // IEEE div: exact
                    w |= (iou > IOUT && (jg0 + jj) > i) ? (1ull << jj) : 0ull;
                }
            }
            mask64[(base + (size_t)i) * NCH + cj] = w;
            __syncthreads();                            // slice reuse next iter
        }
    }
    __threadfence();
    grid.sync();

    // ================= P4: greedy scan + top-300 (R7 k4) ===============
    if (blk < NIMG && tid < 64) {
        const uint32_t* mask = (const uint32_t*)mask64;
        int img = blk;
        int lane = tid;                                 // wave 0 only
        int n = n_arr[img];
        size_t cbase = (size_t)img * NCAND;
        const uint32_t* rowp = mask + cbase * 64 + lane;
        float* outp = out + (size_t)img * NDET * 6;

        uint32_t removed = 0;
        int kcnt = 0;
        constexpr int PF = 32;
        uint32_t buf[PF];
#pragma unroll
        for (int k = 0; k < PF; ++k) buf[k] = rowp[(size_t)k * 64];
        for (int ib = 0; ib < n; ib += PF) {
#pragma unroll
            for (int k = 0; k < PF; ++k) {
                int i = ib + k;
                uint32_t row = buf[k];
                int pi = i + PF; if (pi > NCAND - 1) pi = NCAND - 1;
                buf[k] = rowp[(size_t)pi * 64];
                // blocked layout: word at lane i>>5, bit i&31. i uniform.
                uint32_t w = (uint32_t)__builtin_amdgcn_readlane((int)removed, i >> 5);
                uint32_t kept = ((w >> (i & 31)) & 1u) ^ 1u;
                kcnt += (int)kept;                      // phantom i>=n harmless
                removed |= row & (0u - kept);
            }
            if (kcnt >= NDET) break;                    // uniform early stop
        }

        int j0 = lane << 5;
        uint32_t vmask = (j0 + 32 <= n) ? 0xffffffffu
                       : (j0 >= n ? 0u : ((1u << (n - j0)) - 1u));
        uint32_t keptw = ~removed & vmask;
        int cntk = __popc(keptw);
        int pre = cntk;
        for (int d = 1; d < 64; d <<= 1) {              // inclusive prefix
            int tv = __shfl_up(pre, d);
            if (lane >= d) pre += tv;
        }
        int total = __shfl(pre, 63);
        int r = pre - cntk;                             // exclusive prefix
        uint32_t wvb = keptw;
        while (wvb) {
            int b = __builtin_ctz(wvb);
            wvb &= wvb - 1;
            if (r >= NDET) break;
            int j = j0 + b;
            float* o = outp + (size_t)r * 6;
            o[0] = rx1[cbase + j]; o[1] = ry1[cbase + j];
            o[2] = rx2[cbase + j]; o[3] = ry2[cbase + j];
            o[4] = score[cbase + j]; o[5] = (float)label[cbase + j];
            ++r;
        }
        int nk = total < NDET ? total : NDET;
        for (int idx = nk * 6 + lane; idx < NDET * 6; idx += 64) outp[idx] = 0.0f;
    }
}

// ---------------- launch ----------------
extern "C" void kernel_launch(void* const* d_in, const int* in_sizes, int n_in,
                              void* d_out, int out_size, void* d_ws, size_t ws_size,
                              hipStream_t stream) {
    const float* pred = (const float*)d_in[0];
    float* out = (float*)d_out;
    char* w = (char*)d_ws;

    const size_t A_CNT = 0;                                // 8*32 ints (padded)
    const size_t A_N   = 1024;                             // 8 ints
    const size_t A_RS  = 1280;
    const size_t SZ_RAW = (size_t)NIMG * CAPRAW * 4;       // 128 KiB
    const size_t A_RF  = A_RS + SZ_RAW;
    const size_t SA    = A_RF + SZ_RAW;
    const size_t SZ_S  = (size_t)NIMG * NCAND * 4;         // 64 KiB each

    int*   cnt   = (int*)(w + A_CNT);
    int*   n_arr = (int*)(w + A_N);
    float* raw_s = (float*)(w + A_RS);
    int*   raw_f = (int*)(w + A_RF);
    float* score = (float*)(w + SA + 0 * SZ_S);
    int*   label = (int*)(w + SA + 1 * SZ_S);
    float* ox1   = (float*)(w + SA + 2 * SZ_S);
    float* oy1   = (float*)(w + SA + 3 * SZ_S);
    float* ox2   = (float*)(w + SA + 4 * SZ_S);
    float* oy2   = (float*)(w + SA + 5 * SZ_S);
    float* area  = (float*)(w + SA + 6 * SZ_S);
    float* rx1   = (float*)(w + SA + 7 * SZ_S);
    float* ry1   = (float*)(w + SA + 8 * SZ_S);
    float* rx2   = (float*)(w + SA + 9 * SZ_S);
    float* ry2   = (float*)(w + SA + 10 * SZ_S);
    uint64_t* mask64 = (uint64_t*)(w + SA + 11 * SZ_S);    // 8*2048*32*8 = 4 MiB

    hipMemsetAsync(cnt, 0, NIMG * CSTRIDE * sizeof(int), stream);

    void* args[] = {
        (void*)&pred, (void*)&out, (void*)&cnt, (void*)&n_arr,
        (void*)&raw_s, (void*)&raw_f, (void*)&score, (void*)&label,
        (void*)&ox1, (void*)&oy1, (void*)&ox2, (void*)&oy2, (void*)&area,
        (void*)&rx1, (void*)&ry1, (void*)&rx2, (void*)&ry2, (void*)&mask64,
    };
    hipLaunchCooperativeKernel((const void*)mega, dim3(NBLK), dim3(NTHR),
                               args, 0, stream);
}

// Round 9
// 182.546 us; speedup vs baseline: 2.0406x; 2.0406x over previous
//
#include <hip/hip_runtime.h>
#include <stdint.h>

#define CONF 0.96f
#define IOUT 0.45f
#define NA 25200
#define DIM 85
#define NC 80
#define NIMG 8
#define NCAND 2048
#define CAPRAW 4096
#define NDET 300
#define CSTRIDE 32                    // cnt[img*CSTRIDE]: 128 B between counters
#define CH 64                         // mask tile edge
#define NCH (NCAND / CH)              // 32 chunks

// ---------------- K1: coalesced filter + hot-anchor compaction ---------
// Stage 112 anchors via float4 into LDS (4 blocks/CU), compact anchors
// with obj>CONF (~4.5 of 112) into a hot list, sweep only hot x 80.
#define APB 112
#define BCAP 256                      // block candidate cap (E=7.3, P(>256)~0)
__global__ __launch_bounds__(256) void k1_filter(
    const float* __restrict__ pred, int* __restrict__ cnt,
    float* __restrict__ raw_s, int* __restrict__ raw_f) {
    __shared__ float tile[APB * DIM];  // 38080 B
    __shared__ int   hot[APB];         // 448 B
    __shared__ float l_s[BCAP];
    __shared__ int   l_f[BCAP];
    __shared__ int   l_hot, l_cnt, l_base;   // total LDS 40588 B -> 4 blk/CU
    int tid = threadIdx.x;
    int img = blockIdx.y;
    int a0 = blockIdx.x * APB;        // anchor base within this image
    if (tid == 0) { l_hot = 0; l_cnt = 0; }

    const float4* src = (const float4*)(pred + ((size_t)img * NA + a0) * DIM);
    float4* dst = (float4*)tile;
    for (int i = tid; i < (APB * DIM / 4); i += 256) dst[i] = src[i];
    __syncthreads();

    // hot-anchor detect: obj > CONF (exactly the reference's obj gate)
    if (tid < APB) {
        float obj = tile[tid * DIM + 4];
        if (obj > CONF) { int p = atomicAdd(&l_hot, 1); hot[p] = tid; }
    }
    __syncthreads();
    int nh = l_hot;
    int items = nh * NC;              // typically ~360 -> 2 iterations
    for (int w = tid; w < items; w += 256) {
        int hi = w / NC;
        int c = w - hi * NC;
        int al = hot[hi];
        float obj = tile[al * DIM + 4];
        float s = tile[al * DIM + 5 + c] * obj;
        if (s > CONF) {               // obj>CONF already guaranteed
            int p = atomicAdd(&l_cnt, 1);
            if (p < BCAP) { l_s[p] = s; l_f[p] = (a0 + al) * NC + c; }
        }
    }
    __syncthreads();
    int c = l_cnt; if (c > BCAP) c = BCAP;
    if (tid == 0) l_base = c ? atomicAdd(&cnt[img * CSTRIDE], c) : 0;
    __syncthreads();
    int base = l_base;
    for (int i = tid; i < c; i += 256) {
        int pos = base + i;
        if (pos < CAPRAW) {
            raw_s[img * CAPRAW + pos] = l_s[i];
            raw_f[img * CAPRAW + pos] = l_f[i];
        }
    }
}

// ---------------- K2: O(n^2) rank sort, LDS-broadcast inner loop -------
// Keys distinct (flat idx in low bits) -> rank is a permutation; scatter
// to rank = exact descending sort, tie semantics identical to top_k.
__global__ __launch_bounds__(256) void k2_rank(
    const float* __restrict__ pred,
    const int* __restrict__ cnt, int* __restrict__ n_arr,
    const float* __restrict__ raw_s, const int* __restrict__ raw_f,
    float* __restrict__ score, int* __restrict__ label,
    float* __restrict__ ox1, float* __restrict__ oy1,
    float* __restrict__ ox2, float* __restrict__ oy2,
    float* __restrict__ area,
    float* __restrict__ rx1, float* __restrict__ ry1,
    float* __restrict__ rx2, float* __restrict__ ry2) {
    __shared__ uint64_t keys[CAPRAW];             // 32 KB
    int img = blockIdx.y;
    int tid = threadIdx.x;
    int m = cnt[img * CSTRIDE]; if (m > CAPRAW) m = CAPRAW;
    if (blockIdx.x == 0 && tid == 0) n_arr[img] = m < NCAND ? m : NCAND;

    const float* rs = raw_s + img * CAPRAW;
    const int*   rf = raw_f + img * CAPRAW;
    for (int j = tid; j < CAPRAW; j += 256) {
        uint64_t k = 0;
        if (j < m)
            k = ((uint64_t)__float_as_uint(rs[j]) << 32) | (uint32_t)(~(uint32_t)rf[j]);
        keys[j] = k;
    }
    __syncthreads();
    if (blockIdx.x * 256 >= m) return;            // block-uniform exit

    int idx = blockIdx.x * 256 + tid;
    bool valid = idx < m;
    uint64_t my = keys[idx];                      // 0 for invalid threads
    int mt = (m + 7) & ~7;                        // pad keys are 0: never count
    int rank = 0;
#pragma unroll 8
    for (int j = 0; j < mt; ++j) rank += (keys[j] > my) ? 1 : 0;

    if (valid && rank < NCAND) {
        float s = __uint_as_float((uint32_t)(my >> 32));
        uint32_t myf = ~((uint32_t)my);
        int anchor = (int)(myf / NC);
        int lab = (int)(myf - (uint32_t)anchor * NC);
        const float* p = pred + ((size_t)img * NA + anchor) * DIM;
        float cx = p[0], cy = p[1], wv = p[2], hv = p[3];
        float x1 = cx - 0.5f * wv, y1 = cy - 0.5f * hv;
        float x2 = cx + 0.5f * wv, y2 = cy + 0.5f * hv;
        float off = (float)lab * 4.0f;
        size_t o = (size_t)img * NCAND + rank;
        score[o] = s; label[o] = lab;
        rx1[o] = x1; ry1[o] = y1; rx2[o] = x2; ry2[o] = y2;
        float o1 = x1 + off, o2 = y1 + off, o3 = x2 + off, o4 = y2 + off;
        ox1[o] = o1; oy1[o] = o2; ox2[o] = o3; oy2[o] = o4;
        area[o] = (o3 - o1) * (o4 - o2);   // same op order as reference
    }
}

// ---------------- K3: 64x64 tiles, WRITE-ALL (no memset needed) --------
// Grid (1024, 8): every (ci,cj) pair; inactive tiles (cj<ci or past n)
// store literal 0, so every (row,word) is written exactly once. Zero
// boxes (i>=n or j>=n) give inter=0 -> iou=0 exactly: never suppress.
// BLOCKED layout: row i u64 word c covers j in [64c,64c+64); u32 view
// lane l owns j in [32l,32l+32).
__global__ __launch_bounds__(64) void k3_mask(
    const int* __restrict__ n_arr,
    const float* __restrict__ ox1, const float* __restrict__ oy1,
    const float* __restrict__ ox2, const float* __restrict__ oy2,
    const float* __restrict__ area, uint64_t* __restrict__ mask64) {
    __shared__ float jx1[CH], jy1[CH], jx2[CH], jy2[CH], jar[CH];
    int img = blockIdx.y;
    int n = n_arr[img];
    int ci = blockIdx.x >> 5, cj = blockIdx.x & 31;
    int t = threadIdx.x;
    size_t base = (size_t)img * NCAND;
    int i = ci * CH + t;
    uint64_t w = 0;
    if (cj >= ci && ci * CH < n && cj * CH < n) {  // block-uniform
        {
            int j = cj * CH + t;
            float x1 = 0.f, y1 = 0.f, x2 = 0.f, y2 = 0.f, ar = 0.f;
            if (j < n) {
                x1 = ox1[base + j]; y1 = oy1[base + j];
                x2 = ox2[base + j]; y2 = oy2[base + j]; ar = area[base + j];
            }
            jx1[t] = x1; jy1[t] = y1; jx2[t] = x2; jy2[t] = y2; jar[t] = ar;
        }
        __syncthreads();
        float ax1 = 0.f, ay1 = 0.f, ax2 = 0.f, ay2 = 0.f, aar = 0.f;
        if (i < n) {
            ax1 = ox1[base + i]; ay1 = oy1[base + i];
            ax2 = ox2[base + i]; ay2 = oy2[base + i]; aar = area[base + i];
        }
        int jg0 = cj * CH;
#pragma unroll 8
        for (int jj = 0; jj < CH; ++jj) {
            float ltx = fmaxf(ax1, jx1[jj]), lty = fmaxf(ay1, jy1[jj]);
            float rbx = fminf(ax2, jx2[jj]), rby = fminf(ay2, jy2[jj]);
            float ww = fmaxf(rbx - ltx, 0.f), hh = fmaxf(rby - lty, 0.f);
            float inter = ww * hh;
            float iou = inter / (aar + jar[jj] - inter + 1e-9f);  // IEEE div: exact
            w |= (iou > IOUT && (jg0 + jj) > i) ? (1ull << jj) : 0ull;
        }
    }
    mask64[(base + (size_t)i) * NCH + cj] = w;
}

// ---------------- K4: serial greedy scan + top-300 output --------------
// One wave per image; early stop at 300 kept. Blocked layout: removed
// register lane l holds bits j = 32l + b.
__global__ void k4_scan(const int* __restrict__ n_arr,
                        const uint32_t* __restrict__ mask,
                        const float* __restrict__ score, const int* __restrict__ label,
                        const float* __restrict__ rx1, const float* __restrict__ ry1,
                        const float* __restrict__ rx2, const float* __restrict__ ry2,
                        float* __restrict__ out) {
    int img = blockIdx.x;
    int lane = threadIdx.x;   // 64 threads = 1 wave
    int n = n_arr[img];
    size_t cbase = (size_t)img * NCAND;
    const uint32_t* rowp = mask + cbase * 64 + lane;
    float* outp = out + (size_t)img * NDET * 6;

    uint32_t removed = 0;
    int kcnt = 0;
    constexpr int PF = 32;           // prefetch depth (static indices -> regs)
    uint32_t buf[PF];
#pragma unroll
    for (int k = 0; k < PF; ++k) buf[k] = rowp[(size_t)k * 64];
    for (int ib = 0; ib < n; ib += PF) {
#pragma unroll
        for (int k = 0; k < PF; ++k) {
            int i = ib + k;
            uint32_t row = buf[k];
            int pi = i + PF; if (pi > NCAND - 1) pi = NCAND - 1;  // uniform, SALU
            buf[k] = rowp[(size_t)pi * 64];     // clamped dup never consumed
            // kept(i)? blocked layout: word at lane i>>5, bit i&31. i uniform.
            uint32_t w = (uint32_t)__builtin_amdgcn_readlane((int)removed, i >> 5);
            uint32_t kept = ((w >> (i & 31)) & 1u) ^ 1u;
            kcnt += (int)kept;                   // phantom i>=n harmless (row 0)
            removed |= row & (0u - kept);
        }
        if (kcnt >= NDET) break;                 // uniform early stop
    }

    // Emit kept in sorted order. Lane l covers j in [32l, 32l+32) ->
    // global rank = exclusive lane-prefix of popcounts + in-word prefix.
    int j0 = lane << 5;
    uint32_t vmask = (j0 + 32 <= n) ? 0xffffffffu
                   : (j0 >= n ? 0u : ((1u << (n - j0)) - 1u));
    uint32_t keptw = ~removed & vmask;
    int cntk = __popc(keptw);
    int pre = cntk;
    for (int d = 1; d < 64; d <<= 1) {           // inclusive shuffle prefix
        int tv = __shfl_up(pre, d);
        if (lane >= d) pre += tv;
    }
    int total = __shfl(pre, 63);
    int r = pre - cntk;                          // exclusive prefix
    uint32_t wv = keptw;
    while (wv) {
        int b = __builtin_ctz(wv);
        wv &= wv - 1;
        if (r >= NDET) break;
        int j = j0 + b;
        float* o = outp + (size_t)r * 6;
        o[0] = rx1[cbase + j]; o[1] = ry1[cbase + j];
        o[2] = rx2[cbase + j]; o[3] = ry2[cbase + j];
        o[4] = score[cbase + j]; o[5] = (float)label[cbase + j];
        ++r;
    }
    int nk = total < NDET ? total : NDET;
    for (int idx = nk * 6 + lane; idx < NDET * 6; idx += 64) outp[idx] = 0.0f;
}

// ---------------- launch ----------------
extern "C" void kernel_launch(void* const* d_in, const int* in_sizes, int n_in,
                              void* d_out, int out_size, void* d_ws, size_t ws_size,
                              hipStream_t stream) {
    const float* pred = (const float*)d_in[0];
    float* out = (float*)d_out;
    char* w = (char*)d_ws;

    const size_t A_CNT = 0;                                // 8*32 ints (padded)
    const size_t A_N   = 1024;                             // 8 ints
    const size_t A_RS  = 1280;
    const size_t SZ_RAW = (size_t)NIMG * CAPRAW * 4;       // 128 KiB
    const size_t A_RF  = A_RS + SZ_RAW;
    const size_t SA    = A_RF + SZ_RAW;
    const size_t SZ_S  = (size_t)NIMG * NCAND * 4;         // 64 KiB each

    int*   cnt   = (int*)(w + A_CNT);
    int*   n_arr = (int*)(w + A_N);
    float* raw_s = (float*)(w + A_RS);
    int*   raw_f = (int*)(w + A_RF);
    float* score = (float*)(w + SA + 0 * SZ_S);
    int*   label = (int*)(w + SA + 1 * SZ_S);
    float* ox1   = (float*)(w + SA + 2 * SZ_S);
    float* oy1   = (float*)(w + SA + 3 * SZ_S);
    float* ox2   = (float*)(w + SA + 4 * SZ_S);
    float* oy2   = (float*)(w + SA + 5 * SZ_S);
    float* area  = (float*)(w + SA + 6 * SZ_S);
    float* rx1   = (float*)(w + SA + 7 * SZ_S);
    float* ry1   = (float*)(w + SA + 8 * SZ_S);
    float* rx2   = (float*)(w + SA + 9 * SZ_S);
    float* ry2   = (float*)(w + SA + 10 * SZ_S);
    uint64_t* mask64 = (uint64_t*)(w + SA + 11 * SZ_S);    // 8*2048*32*8 = 4 MiB
    uint32_t* mask32 = (uint32_t*)mask64;

    hipMemsetAsync(cnt, 0, NIMG * CSTRIDE * sizeof(int), stream);
    dim3 g1(NA / APB, NIMG);                               // 225 x 8
    k1_filter<<<g1, 256, 0, stream>>>(pred, cnt, raw_s, raw_f);
    dim3 g2(CAPRAW / 256, NIMG);                           // 16 x 8
    k2_rank<<<g2, 256, 0, stream>>>(pred, cnt, n_arr, raw_s, raw_f,
        score, label, ox1, oy1, ox2, oy2, area, rx1, ry1, rx2, ry2);
    dim3 g3(NCH * NCH, NIMG);                              // 1024 x 8, write-all
    k3_mask<<<g3, CH, 0, stream>>>(n_arr, ox1, oy1, ox2, oy2, area, mask64);
    k4_scan<<<NIMG, 64, 0, stream>>>(n_arr, mask32, score, label,
        rx1, ry1, rx2, ry2, out);
}